// Round 1
// baseline (767.663 us; speedup 1.0000x reference)
//
#include <hip/hip_runtime.h>

typedef unsigned short u16;
typedef unsigned int u32;
typedef __attribute__((ext_vector_type(4))) float f32x4;
typedef __attribute__((ext_vector_type(8))) __bf16 bf16x8;
typedef __attribute__((ext_vector_type(8))) u16 u16x8;

// round-to-nearest-even f32 -> bf16 bit pattern
__device__ __forceinline__ u16 f2bf(float x) {
  u32 u = __float_as_uint(x);
  u32 r = (u + 0x7FFFu + ((u >> 16) & 1u)) >> 16;
  return (u16)r;
}

// async global->LDS, 16B per lane. LDS dest must be wave-uniform base + lane*16
// (all call sites below index LDS by threadIdx.x*16 + wave-uniform offset).
__device__ __forceinline__ void gl16(const void* g, void* l) {
  auto* gp = (__attribute__((address_space(1))) u32*)(g);
  auto* lp = (__attribute__((address_space(3))) u32*)(l);
  __builtin_amdgcn_global_load_lds(gp, lp, 16, 0, 0);
}

__device__ __forceinline__ f32x4 mfma16(bf16x8 a, bf16x8 b, f32x4 c) {
  return __builtin_amdgcn_mfma_f32_16x16x32_bf16(a, b, c, 0, 0, 0);
}

// ---------------- conversion kernels ----------------

__global__ void k_cvt(const float* __restrict__ in, u16* __restrict__ out, int n8) {
  int i = blockIdx.x * 256 + threadIdx.x;
  if (i >= n8) return;
  const float4* p = (const float4*)in + (long)i * 2;
  float4 a = p[0], b = p[1];
  u16x8 v;
  v[0] = f2bf(a.x); v[1] = f2bf(a.y); v[2] = f2bf(a.z); v[3] = f2bf(a.w);
  v[4] = f2bf(b.x); v[5] = f2bf(b.y); v[6] = f2bf(b.z); v[7] = f2bf(b.w);
  *(u16x8*)(out + (long)i * 8) = v;
}

// W_cc (51x4096) -> bf16 padded to 64x4096 (rows 51..63 = 0)
__global__ void k_cvt_wcc(const float* __restrict__ wcc, u16* __restrict__ out, int n8) {
  int i = blockIdx.x * 256 + threadIdx.x;
  if (i >= n8) return;
  long base = (long)i * 8;
  int row = (int)(base >> 12);
  int col = (int)(base & 4095);
  u16x8 v;
  if (row < 51) {
    const float4* p = (const float4*)(wcc + (long)row * 4096 + col);
    float4 a = p[0], b = p[1];
    v[0] = f2bf(a.x); v[1] = f2bf(a.y); v[2] = f2bf(a.z); v[3] = f2bf(a.w);
    v[4] = f2bf(b.x); v[5] = f2bf(b.y); v[6] = f2bf(b.z); v[7] = f2bf(b.w);
  } else {
#pragma unroll
    for (int j = 0; j < 8; ++j) v[j] = 0;
  }
  *(u16x8*)(out + base) = v;
}

// ---------------- GEMM1: edge_rep = relu(edge_ctx @ W_pe.T + b_pe) -> bf16 ----------------
// A: [5000][512] bf16, B(W_pe): [1024][512] bf16, out: [5000][1024] bf16
__global__ __launch_bounds__(256, 2) void k_gemm1(const u16* __restrict__ A, const u16* __restrict__ B,
                                                  const float* __restrict__ bias, u16* __restrict__ outp) {
  __shared__ char lds[16384];
  char* sA = lds;
  char* sB = lds + 8192;
  int bx = blockIdx.x;
  int rb = bx >> 3, nb = bx & 7;
  int rowBase = rb * 128, nBase = nb * 128;
  int t = threadIdx.x, lane = t & 63, wid = t >> 6;
  int wr = wid >> 1, wc = wid & 1, lm = lane & 15, lg = lane >> 4;
  int ar0 = t >> 2, ar1 = 64 + ar0, c4 = t & 3;
  int sw0 = (c4 * 16) ^ (((ar0 >> 1) & 3) << 4);
  int sw1 = (c4 * 16) ^ (((ar1 >> 1) & 3) << 4);
  const char* aS0 = (const char*)(A + (long)min(rowBase + ar0, 4999) * 512) + sw0;
  const char* aS1 = (const char*)(A + (long)min(rowBase + ar1, 4999) * 512) + sw1;
  const char* bS0 = (const char*)(B + (long)(nBase + ar0) * 512) + sw0;
  const char* bS1 = (const char*)(B + (long)(nBase + ar1) * 512) + sw1;
  char* dA0 = sA + t * 16; char* dA1 = dA0 + 4096;
  char* dB0 = sB + t * 16; char* dB1 = dB0 + 4096;
  int aOff[4], bOff[4];
#pragma unroll
  for (int mi = 0; mi < 4; ++mi) { int r = wr * 64 + mi * 16 + lm; aOff[mi] = r * 64 + ((lg * 16) ^ (((r >> 1) & 3) << 4)); }
#pragma unroll
  for (int ni = 0; ni < 4; ++ni) { int r = wc * 64 + ni * 16 + lm; bOff[ni] = r * 64 + ((lg * 16) ^ (((r >> 1) & 3) << 4)); }
  f32x4 acc[4][4] = {};
  for (int kk = 0; kk < 512; kk += 32) {
    gl16(aS0 + kk * 2, dA0);
    gl16(aS1 + kk * 2, dA1);
    gl16(bS0 + kk * 2, dB0);
    gl16(bS1 + kk * 2, dB1);
    __syncthreads();
    bf16x8 af[4], bv[4];
#pragma unroll
    for (int mi = 0; mi < 4; ++mi) af[mi] = *(const bf16x8*)(sA + aOff[mi]);
#pragma unroll
    for (int ni = 0; ni < 4; ++ni) bv[ni] = *(const bf16x8*)(sB + bOff[ni]);
#pragma unroll
    for (int mi = 0; mi < 4; ++mi)
#pragma unroll
      for (int ni = 0; ni < 4; ++ni)
        acc[mi][ni] = mfma16(af[mi], bv[ni], acc[mi][ni]);
    __syncthreads();
  }
#pragma unroll
  for (int mi = 0; mi < 4; ++mi)
#pragma unroll
    for (int ni = 0; ni < 4; ++ni) {
      int n = nBase + wc * 64 + ni * 16 + lm;
      float bvv = bias[n];
#pragma unroll
      for (int rg = 0; rg < 4; ++rg) {
        int r = rowBase + wr * 64 + mi * 16 + lg * 4 + rg;
        if (r < 5000) {
          float v = acc[mi][ni][rg] + bvv;
          v = v > 0.f ? v : 0.f;
          outp[(long)r * 1024 + n] = f2bf(v);
        }
      }
    }
}

// ---------------- fused: GEMM2 + bias + *union + GEMM3 + bias + freq ----------------
// grid = 157 row-blocks * 4 pc-slices. Each block: 128 rows x 1024 pc cols.
__global__ __launch_bounds__(256, 2) void k_fused(
    const u16* __restrict__ erep,  // [5000][1024] bf16
    const u16* __restrict__ wpc,   // [4096][1024] bf16
    const u16* __restrict__ wcc,   // [64][4096] bf16 (padded)
    const float* __restrict__ un,  // [20000][4096] f32
    const float* __restrict__ bpc, const float* __restrict__ bcc,
    const float* __restrict__ freq, const int* __restrict__ preds,
    const int* __restrict__ pidx, float* __restrict__ outp) {
  __shared__ char lds[49664];
  char* sA = lds;            // 8 KB  [128][32] bf16 swizzled
  char* sB = lds + 8192;     // 8 KB  [128][32] bf16 swizzled
  char* sW = lds;            // 16 KB [64][128] bf16 swizzled (aliases sA+sB)
  char* sU = lds + 16384;    // 32 KB [128][128] bf16 swizzled
  int* sLbl = (int*)(lds + 49152);  // 128 ints

  int bx = blockIdx.x;
  int rb = bx >> 2, ps = bx & 3;
  int rowBase = rb * 128;
  int t = threadIdx.x, lane = t & 63, wid = t >> 6;
  int wr = wid >> 1, wc = wid & 1, lm = lane & 15, lg = lane >> 4;

  if (t < 128) {
    int rG = min(rowBase + t, 19999);
    sLbl[t] = preds[pidx[2 * rG]] * 151 + preds[pidx[2 * rG + 1]];
  }

  int ar0 = t >> 2, ar1 = 64 + ar0, c4 = t & 3;
  int rG0 = min(rowBase + ar0, 19999), rG1 = min(rowBase + ar1, 19999);
  int hi0 = pidx[2 * rG0], ti0 = pidx[2 * rG0 + 1];
  int hi1 = pidx[2 * rG1], ti1 = pidx[2 * rG1 + 1];
  int sw0 = (c4 * 16) ^ (((ar0 >> 1) & 3) << 4);
  int sw1 = (c4 * 16) ^ (((ar1 >> 1) & 3) << 4);
  const char* aR0h = (const char*)(erep + (long)hi0 * 1024) + sw0;
  const char* aR0t = (const char*)(erep + (long)ti0 * 1024) + sw0;
  const char* aR1h = (const char*)(erep + (long)hi1 * 1024) + sw1;
  const char* aR1t = (const char*)(erep + (long)ti1 * 1024) + sw1;
  char* dA0 = sA + t * 16; char* dA1 = dA0 + 4096;
  char* dB0 = sB + t * 16; char* dB1 = dB0 + 4096;

  int aOff[4], bOff[4];
#pragma unroll
  for (int mi = 0; mi < 4; ++mi) { int r = wr * 64 + mi * 16 + lm; aOff[mi] = r * 64 + ((lg * 16) ^ (((r >> 1) & 3) << 4)); }
#pragma unroll
  for (int ni = 0; ni < 4; ++ni) { int r = wc * 64 + ni * 16 + lm; bOff[ni] = r * 64 + ((lg * 16) ^ (((r >> 1) & 3) << 4)); }

  f32x4 outAcc[2][4] = {};

  for (int chk = 0; chk < 8; ++chk) {
    int pcBase = ps * 1024 + chk * 128;
    f32x4 acc[4][4] = {};
    const char* bS0 = (const char*)(wpc + (long)(pcBase + ar0) * 1024) + sw0;
    const char* bS1 = (const char*)(wpc + (long)(pcBase + ar1) * 1024) + sw1;

    for (int kk = 0; kk < 1024; kk += 32) {
      gl16((kk < 512 ? aR0h : aR0t) + kk * 2, dA0);
      gl16((kk < 512 ? aR1h : aR1t) + kk * 2, dA1);
      gl16(bS0 + kk * 2, dB0);
      gl16(bS1 + kk * 2, dB1);
      __syncthreads();
      bf16x8 af[4], bv[4];
#pragma unroll
      for (int mi = 0; mi < 4; ++mi) af[mi] = *(const bf16x8*)(sA + aOff[mi]);
#pragma unroll
      for (int ni = 0; ni < 4; ++ni) bv[ni] = *(const bf16x8*)(sB + bOff[ni]);
#pragma unroll
      for (int mi = 0; mi < 4; ++mi)
#pragma unroll
        for (int ni = 0; ni < 4; ++ni)
          acc[mi][ni] = mfma16(af[mi], bv[ni], acc[mi][ni]);
      __syncthreads();
    }

    // stage W_cc chunk [64 rows x 128 cols] into sW (aliases sA/sB, safe: K-loop done)
#pragma unroll
    for (int i = 0; i < 4; ++i) {
      int cc = t + i * 256;
      int row = cc >> 4, c16 = cc & 15;
      const char* src = (const char*)(wcc + (long)row * 4096) + pcBase * 2 + ((c16 * 16) ^ ((row & 7) << 4));
      gl16(src, sW + cc * 16);
    }

    // epilogue: +b_pc, *union, ->bf16 into sU
#pragma unroll
    for (int mi = 0; mi < 4; ++mi)
#pragma unroll
      for (int ni = 0; ni < 4; ++ni) {
        int pl = wc * 64 + ni * 16 + lm;
        float bvv = bpc[pcBase + pl];
#pragma unroll
        for (int rg = 0; rg < 4; ++rg) {
          int r = wr * 64 + mi * 16 + lg * 4 + rg;
          long rG = min(rowBase + r, 19999);
          float u = un[rG * 4096 + pcBase + pl];
          float v = (acc[mi][ni][rg] + bvv) * u;
          *(u16*)(sU + r * 256 + ((pl * 2) ^ ((r & 7) << 4))) = f2bf(v);
        }
      }
    __syncthreads();

    // GEMM3 partial: outAcc += sU(128x128) @ sW(64x128)^T ; wave owns rows 32*wid..+31
#pragma unroll
    for (int kb = 0; kb < 4; ++kb) {
      bf16x8 aU[2], bW[4];
#pragma unroll
      for (int m2 = 0; m2 < 2; ++m2) {
        int r = wid * 32 + m2 * 16 + lm;
        aU[m2] = *(const bf16x8*)(sU + r * 256 + ((kb * 64 + lg * 16) ^ ((r & 7) << 4)));
      }
#pragma unroll
      for (int ni = 0; ni < 4; ++ni) {
        int r = ni * 16 + lm;
        bW[ni] = *(const bf16x8*)(sW + r * 256 + ((kb * 64 + lg * 16) ^ ((r & 7) << 4)));
      }
#pragma unroll
      for (int m2 = 0; m2 < 2; ++m2)
#pragma unroll
        for (int ni = 0; ni < 4; ++ni)
          outAcc[m2][ni] = mfma16(aU[m2], bW[ni], outAcc[m2][ni]);
    }
    __syncthreads();
  }

  // final: + b_cc + freq (slice 0 only), atomicAdd partials
#pragma unroll
  for (int m2 = 0; m2 < 2; ++m2)
#pragma unroll
    for (int ni = 0; ni < 4; ++ni)
#pragma unroll
      for (int rg = 0; rg < 4; ++rg) {
        int r = wid * 32 + m2 * 16 + lg * 4 + rg;
        int rG = rowBase + r;
        int c = ni * 16 + lm;
        if (rG < 20000 && c < 51) {
          float v = outAcc[m2][ni][rg];
          if (ps == 0) v += bcc[c] + freq[(long)sLbl[r] * 51 + c];
          atomicAdd(&outp[(long)rG * 51 + c], v);
        }
      }
}

extern "C" void kernel_launch(void* const* d_in, const int* in_sizes, int n_in,
                              void* d_out, int out_size, void* d_ws, size_t ws_size,
                              hipStream_t stream) {
  const float* edge_ctx = (const float*)d_in[0];
  const float* unionf   = (const float*)d_in[1];
  const float* W_pe     = (const float*)d_in[2];
  const float* b_pe     = (const float*)d_in[3];
  const float* W_pc     = (const float*)d_in[4];
  const float* b_pc     = (const float*)d_in[5];
  const float* W_cc     = (const float*)d_in[6];
  const float* b_cc     = (const float*)d_in[7];
  const float* freq     = (const float*)d_in[8];
  const int*   preds    = (const int*)d_in[9];
  const int*   pidx     = (const int*)d_in[10];
  float* out = (float*)d_out;
  char* ws = (char*)d_ws;

  u16* ecb  = (u16*)(ws + 0);         // 5000*512   bf16 edge_ctx
  u16* wpeb = (u16*)(ws + 5120000);   // 1024*512   bf16 W_pe
  u16* erep = (u16*)(ws + 6168576);   // 5000*1024  bf16 edge_rep (relu'd)
  u16* wpcb = (u16*)(ws + 16408576);  // 4096*1024  bf16 W_pc
  u16* wccb = (u16*)(ws + 24797184);  // 64*4096    bf16 W_cc padded

  hipMemsetAsync(d_out, 0, (size_t)out_size * 4, stream);
  k_cvt<<<1250, 256, 0, stream>>>(edge_ctx, ecb, 320000);
  k_cvt<<<256, 256, 0, stream>>>(W_pe, wpeb, 65536);
  k_cvt<<<2048, 256, 0, stream>>>(W_pc, wpcb, 524288);
  k_cvt_wcc<<<128, 256, 0, stream>>>(W_cc, wccb, 32768);
  k_gemm1<<<320, 256, 0, stream>>>(ecb, wpeb, b_pe, erep);
  k_fused<<<628, 256, 0, stream>>>(erep, wpcb, wccb, unionf, b_pc, b_cc, freq, preds, pidx, out);
}

// Round 2
// 639.703 us; speedup vs baseline: 1.2000x; 1.2000x over previous
//
#include <hip/hip_runtime.h>

typedef unsigned short u16;
typedef unsigned int u32;
typedef __attribute__((ext_vector_type(4))) float f32x4;
typedef __attribute__((ext_vector_type(8))) __bf16 bf16x8;
typedef __attribute__((ext_vector_type(8))) u16 u16x8;

// round-to-nearest-even f32 -> bf16 bit pattern
__device__ __forceinline__ u16 f2bf(float x) {
  u32 u = __float_as_uint(x);
  u32 r = (u + 0x7FFFu + ((u >> 16) & 1u)) >> 16;
  return (u16)r;
}

// async global->LDS, 16B per lane. LDS dest = wave-uniform base + lane*16.
__device__ __forceinline__ void gl16(const void* g, void* l) {
  auto* gp = (__attribute__((address_space(1))) u32*)(g);
  auto* lp = (__attribute__((address_space(3))) u32*)(l);
  __builtin_amdgcn_global_load_lds(gp, lp, 16, 0, 0);
}

__device__ __forceinline__ f32x4 mfma16(bf16x8 a, bf16x8 b, f32x4 c) {
  return __builtin_amdgcn_mfma_f32_16x16x32_bf16(a, b, c, 0, 0, 0);
}

#define WAIT_VM0_BAR() do { \
  asm volatile("s_waitcnt vmcnt(0) lgkmcnt(0)" ::: "memory"); \
  __builtin_amdgcn_s_barrier(); \
} while (0)

// ---------------- conversion kernels ----------------

__global__ void k_cvt(const float* __restrict__ in, u16* __restrict__ out, int n8) {
  int i = blockIdx.x * 256 + threadIdx.x;
  if (i >= n8) return;
  const float4* p = (const float4*)in + (long)i * 2;
  float4 a = p[0], b = p[1];
  u16x8 v;
  v[0] = f2bf(a.x); v[1] = f2bf(a.y); v[2] = f2bf(a.z); v[3] = f2bf(a.w);
  v[4] = f2bf(b.x); v[5] = f2bf(b.y); v[6] = f2bf(b.z); v[7] = f2bf(b.w);
  *(u16x8*)(out + (long)i * 8) = v;
}

// W_cc (51x4096) -> bf16 padded to 64x4096 (rows 51..63 = 0)
__global__ void k_cvt_wcc(const float* __restrict__ wcc, u16* __restrict__ out, int n8) {
  int i = blockIdx.x * 256 + threadIdx.x;
  if (i >= n8) return;
  long base = (long)i * 8;
  int row = (int)(base >> 12);
  int col = (int)(base & 4095);
  u16x8 v;
  if (row < 51) {
    const float4* p = (const float4*)(wcc + (long)row * 4096 + col);
    float4 a = p[0], b = p[1];
    v[0] = f2bf(a.x); v[1] = f2bf(a.y); v[2] = f2bf(a.z); v[3] = f2bf(a.w);
    v[4] = f2bf(b.x); v[5] = f2bf(b.y); v[6] = f2bf(b.z); v[7] = f2bf(b.w);
  } else {
#pragma unroll
    for (int j = 0; j < 8; ++j) v[j] = 0;
  }
  *(u16x8*)(out + base) = v;
}

// one 128x128x32 compute step: 8 ds_read_b128 + 16 MFMA
__device__ __forceinline__ void cstep(const char* sA, const char* sB,
                                      const int (&aOff)[4], const int (&bOff)[4],
                                      f32x4 (&acc)[4][4]) {
  bf16x8 af[4], bv[4];
#pragma unroll
  for (int mi = 0; mi < 4; ++mi) af[mi] = *(const bf16x8*)(sA + aOff[mi]);
#pragma unroll
  for (int ni = 0; ni < 4; ++ni) bv[ni] = *(const bf16x8*)(sB + bOff[ni]);
#pragma unroll
  for (int mi = 0; mi < 4; ++mi)
#pragma unroll
    for (int ni = 0; ni < 4; ++ni)
      acc[mi][ni] = mfma16(af[mi], bv[ni], acc[mi][ni]);
}

// ---------------- GEMM1: edge_rep = relu(edge_ctx @ W_pe.T + b_pe) -> bf16 ----------------
// A: [5000][512] bf16, B(W_pe): [1024][512] bf16, out: [5000][1024] bf16
__global__ __launch_bounds__(256, 2) void k_gemm1(const u16* __restrict__ A, const u16* __restrict__ B,
                                                  const float* __restrict__ bias, u16* __restrict__ outp) {
  __shared__ char lds[32768];
  char* sA0 = lds;
  char* sA1 = lds + 8192;
  char* sB0 = lds + 16384;
  char* sB1 = lds + 24576;
  int bx = blockIdx.x;
  int rb = bx >> 3, nb = bx & 7;
  int rowBase = rb * 128, nBase = nb * 128;
  int t = threadIdx.x, lane = t & 63, wid = t >> 6;
  int wr = wid >> 1, wc = wid & 1, lm = lane & 15, lg = lane >> 4;
  int ar0 = t >> 2, ar1 = 64 + ar0, c4 = t & 3;
  int sw0 = (c4 * 16) ^ (((ar0 >> 1) & 3) << 4);
  int sw1 = (c4 * 16) ^ (((ar1 >> 1) & 3) << 4);
  const char* aS0 = (const char*)(A + (long)min(rowBase + ar0, 4999) * 512) + sw0;
  const char* aS1 = (const char*)(A + (long)min(rowBase + ar1, 4999) * 512) + sw1;
  const char* bS0 = (const char*)(B + (long)(nBase + ar0) * 512) + sw0;
  const char* bS1 = (const char*)(B + (long)(nBase + ar1) * 512) + sw1;
  int t16 = t * 16;
  int aOff[4], bOff[4];
#pragma unroll
  for (int mi = 0; mi < 4; ++mi) { int r = wr * 64 + mi * 16 + lm; aOff[mi] = r * 64 + ((lg * 16) ^ (((r >> 1) & 3) << 4)); }
#pragma unroll
  for (int ni = 0; ni < 4; ++ni) { int r = wc * 64 + ni * 16 + lm; bOff[ni] = r * 64 + ((lg * 16) ^ (((r >> 1) & 3) << 4)); }
  f32x4 acc[4][4] = {};

  // prologue: stage tile 0
  gl16(aS0, sA0 + t16); gl16(aS1, sA0 + 4096 + t16);
  gl16(bS0, sB0 + t16); gl16(bS1, sB0 + 4096 + t16);
  asm volatile("s_waitcnt vmcnt(0)" ::: "memory");
  __builtin_amdgcn_s_barrier();

  for (int kk2 = 0; kk2 < 8; ++kk2) {
    int k0 = kk2 * 64;
    // phase A: stage k0+32 -> buf1, compute buf0
    gl16(aS0 + (k0 + 32) * 2, sA1 + t16); gl16(aS1 + (k0 + 32) * 2, sA1 + 4096 + t16);
    gl16(bS0 + (k0 + 32) * 2, sB1 + t16); gl16(bS1 + (k0 + 32) * 2, sB1 + 4096 + t16);
    cstep(sA0, sB0, aOff, bOff, acc);
    WAIT_VM0_BAR();
    // phase B: stage k0+64 -> buf0, compute buf1
    if (kk2 < 7) {
      gl16(aS0 + (k0 + 64) * 2, sA0 + t16); gl16(aS1 + (k0 + 64) * 2, sA0 + 4096 + t16);
      gl16(bS0 + (k0 + 64) * 2, sB0 + t16); gl16(bS1 + (k0 + 64) * 2, sB0 + 4096 + t16);
    }
    cstep(sA1, sB1, aOff, bOff, acc);
    WAIT_VM0_BAR();
  }

#pragma unroll
  for (int mi = 0; mi < 4; ++mi)
#pragma unroll
    for (int ni = 0; ni < 4; ++ni) {
      int n = nBase + wc * 64 + ni * 16 + lm;
      float bvv = bias[n];
#pragma unroll
      for (int rg = 0; rg < 4; ++rg) {
        int r = rowBase + wr * 64 + mi * 16 + lg * 4 + rg;
        if (r < 5000) {
          float v = acc[mi][ni][rg] + bvv;
          v = v > 0.f ? v : 0.f;
          outp[(long)r * 1024 + n] = f2bf(v);
        }
      }
    }
}

// ---------------- fused: GEMM2 + bias + *union + GEMM3 + bias + freq ----------------
// grid = 157 row-blocks * 8 pc-slices. Each block: 128 rows x 512 pc cols (4 chunks of 128).
__global__ __launch_bounds__(256, 2) void k_fused(
    const u16* __restrict__ erep,  // [5000][1024] bf16
    const u16* __restrict__ wpc,   // [4096][1024] bf16
    const u16* __restrict__ wcc,   // [64][4096] bf16 (padded)
    const float* __restrict__ un,  // [20000][4096] f32
    const float* __restrict__ bpc, const float* __restrict__ bcc,
    const float* __restrict__ freq, const int* __restrict__ preds,
    const int* __restrict__ pidx, float* __restrict__ outp) {
  __shared__ char lds[49664];
  char* sA0 = lds;            // 8 KB
  char* sB0 = lds + 8192;     // 8 KB
  char* sA1 = lds + 16384;    // 8 KB
  char* sB1 = lds + 24576;    // 8 KB
  char* sU = lds;             // 32 KB [128][128] bf16 swizzled (aliases all staging bufs)
  char* sW = lds + 32768;     // 16 KB [64][128] bf16 swizzled
  int* sLbl = (int*)(lds + 49152);  // 128 ints

  int bx = blockIdx.x;
  int rb = bx >> 3, ps = bx & 7;
  int rowBase = rb * 128;
  int t = threadIdx.x, lane = t & 63, wid = t >> 6;
  int wr = wid >> 1, wc = wid & 1, lm = lane & 15, lg = lane >> 4;

  if (t < 128) {
    int rG = min(rowBase + t, 19999);
    sLbl[t] = preds[pidx[2 * rG]] * 151 + preds[pidx[2 * rG + 1]];
  }

  int ar0 = t >> 2, ar1 = 64 + ar0, c4 = t & 3;
  int rG0 = min(rowBase + ar0, 19999), rG1 = min(rowBase + ar1, 19999);
  int hi0 = pidx[2 * rG0], ti0 = pidx[2 * rG0 + 1];
  int hi1 = pidx[2 * rG1], ti1 = pidx[2 * rG1 + 1];
  int sw0 = (c4 * 16) ^ (((ar0 >> 1) & 3) << 4);
  int sw1 = (c4 * 16) ^ (((ar1 >> 1) & 3) << 4);
  const char* aR0h = (const char*)(erep + (long)hi0 * 1024) + sw0;
  const char* aR0t = (const char*)(erep + (long)ti0 * 1024) + sw0;
  const char* aR1h = (const char*)(erep + (long)hi1 * 1024) + sw1;
  const char* aR1t = (const char*)(erep + (long)ti1 * 1024) + sw1;
  int t16 = t * 16;

  int aOff[4], bOff[4];
#pragma unroll
  for (int mi = 0; mi < 4; ++mi) { int r = wr * 64 + mi * 16 + lm; aOff[mi] = r * 64 + ((lg * 16) ^ (((r >> 1) & 3) << 4)); }
#pragma unroll
  for (int ni = 0; ni < 4; ++ni) { int r = wc * 64 + ni * 16 + lm; bOff[ni] = r * 64 + ((lg * 16) ^ (((r >> 1) & 3) << 4)); }

  f32x4 outAcc[2][4] = {};

  for (int chk = 0; chk < 4; ++chk) {
    int pcBase = ps * 512 + chk * 128;
    f32x4 acc[4][4] = {};
    const char* bS0 = (const char*)(wpc + (long)(pcBase + ar0) * 1024) + sw0;
    const char* bS1 = (const char*)(wpc + (long)(pcBase + ar1) * 1024) + sw1;

    // ---- chunk prologue: stage A/B tile k=0 and the W_cc chunk ----
    gl16(aR0h, sA0 + t16); gl16(aR1h, sA0 + 4096 + t16);
    gl16(bS0, sB0 + t16); gl16(bS1, sB0 + 4096 + t16);
#pragma unroll
    for (int i = 0; i < 4; ++i) {
      int cc = t + i * 256;
      int row = cc >> 4, c16 = cc & 15;
      const char* src = (const char*)(wcc + (long)row * 4096) + pcBase * 2 + ((c16 * 16) ^ ((row & 7) << 4));
      gl16(src, sW + cc * 16);
    }
    asm volatile("s_waitcnt vmcnt(0)" ::: "memory");
    __builtin_amdgcn_s_barrier();

    // ---- 2-phase pipelined K-loop: 32 tiles of K=32 ----
    for (int kk2 = 0; kk2 < 16; ++kk2) {
      int kA = kk2 * 64 + 32;   // staged during phase A
      int kB = kk2 * 64 + 64;   // staged during phase B
      {
        const char* a0 = (kA < 512) ? aR0h : aR0t;
        const char* a1 = (kA < 512) ? aR1h : aR1t;
        gl16(a0 + kA * 2, sA1 + t16); gl16(a1 + kA * 2, sA1 + 4096 + t16);
        gl16(bS0 + kA * 2, sB1 + t16); gl16(bS1 + kA * 2, sB1 + 4096 + t16);
      }
      cstep(sA0, sB0, aOff, bOff, acc);
      WAIT_VM0_BAR();
      if (kk2 < 15) {
        const char* a0 = (kB < 512) ? aR0h : aR0t;
        const char* a1 = (kB < 512) ? aR1h : aR1t;
        gl16(a0 + kB * 2, sA0 + t16); gl16(a1 + kB * 2, sA0 + 4096 + t16);
        gl16(bS0 + kB * 2, sB0 + t16); gl16(bS1 + kB * 2, sB0 + 4096 + t16);
      }
      cstep(sA1, sB1, aOff, bOff, acc);
      WAIT_VM0_BAR();
    }

    // ---- epilogue: +b_pc, *union, ->bf16 into sU (overwrites staging bufs) ----
#pragma unroll
    for (int mi = 0; mi < 4; ++mi)
#pragma unroll
      for (int ni = 0; ni < 4; ++ni) {
        int pl = wc * 64 + ni * 16 + lm;
        float bvv = bpc[pcBase + pl];
#pragma unroll
        for (int rg = 0; rg < 4; ++rg) {
          int r = wr * 64 + mi * 16 + lg * 4 + rg;
          long rG = min(rowBase + r, 19999);
          float u = un[rG * 4096 + pcBase + pl];
          float v = (acc[mi][ni][rg] + bvv) * u;
          *(u16*)(sU + r * 256 + ((pl * 2) ^ ((r & 7) << 4))) = f2bf(v);
        }
      }
    __syncthreads();

    // ---- GEMM3 partial: outAcc += sU(128x128) @ sW(64x128)^T ----
#pragma unroll
    for (int kb = 0; kb < 4; ++kb) {
      bf16x8 aU[2], bW[4];
#pragma unroll
      for (int m2 = 0; m2 < 2; ++m2) {
        int r = wid * 32 + m2 * 16 + lm;
        aU[m2] = *(const bf16x8*)(sU + r * 256 + ((kb * 64 + lg * 16) ^ ((r & 7) << 4)));
      }
#pragma unroll
      for (int ni = 0; ni < 4; ++ni) {
        int r = ni * 16 + lm;
        bW[ni] = *(const bf16x8*)(sW + r * 256 + ((kb * 64 + lg * 16) ^ ((r & 7) << 4)));
      }
#pragma unroll
      for (int m2 = 0; m2 < 2; ++m2)
#pragma unroll
        for (int ni = 0; ni < 4; ++ni)
          outAcc[m2][ni] = mfma16(aU[m2], bW[ni], outAcc[m2][ni]);
    }
    __syncthreads();
  }

  // final: + b_cc + freq (slice 0 only), atomicAdd partials
#pragma unroll
  for (int m2 = 0; m2 < 2; ++m2)
#pragma unroll
    for (int ni = 0; ni < 4; ++ni)
#pragma unroll
      for (int rg = 0; rg < 4; ++rg) {
        int r = wid * 32 + m2 * 16 + lg * 4 + rg;
        int rG = rowBase + r;
        int c = ni * 16 + lm;
        if (rG < 20000 && c < 51) {
          float v = outAcc[m2][ni][rg];
          if (ps == 0) v += bcc[c] + freq[(long)sLbl[r] * 51 + c];
          atomicAdd(&outp[(long)rG * 51 + c], v);
        }
      }
}

extern "C" void kernel_launch(void* const* d_in, const int* in_sizes, int n_in,
                              void* d_out, int out_size, void* d_ws, size_t ws_size,
                              hipStream_t stream) {
  const float* edge_ctx = (const float*)d_in[0];
  const float* unionf   = (const float*)d_in[1];
  const float* W_pe     = (const float*)d_in[2];
  const float* b_pe     = (const float*)d_in[3];
  const float* W_pc     = (const float*)d_in[4];
  const float* b_pc     = (const float*)d_in[5];
  const float* W_cc     = (const float*)d_in[6];
  const float* b_cc     = (const float*)d_in[7];
  const float* freq     = (const float*)d_in[8];
  const int*   preds    = (const int*)d_in[9];
  const int*   pidx     = (const int*)d_in[10];
  float* out = (float*)d_out;
  char* ws = (char*)d_ws;

  u16* ecb  = (u16*)(ws + 0);         // 5000*512   bf16 edge_ctx
  u16* wpeb = (u16*)(ws + 5120000);   // 1024*512   bf16 W_pe
  u16* erep = (u16*)(ws + 6168576);   // 5000*1024  bf16 edge_rep (relu'd)
  u16* wpcb = (u16*)(ws + 16408576);  // 4096*1024  bf16 W_pc
  u16* wccb = (u16*)(ws + 24797184);  // 64*4096    bf16 W_cc padded

  hipMemsetAsync(d_out, 0, (size_t)out_size * 4, stream);
  k_cvt<<<1250, 256, 0, stream>>>(edge_ctx, ecb, 320000);
  k_cvt<<<256, 256, 0, stream>>>(W_pe, wpeb, 65536);
  k_cvt<<<2048, 256, 0, stream>>>(W_pc, wpcb, 524288);
  k_cvt_wcc<<<128, 256, 0, stream>>>(W_cc, wccb, 32768);
  k_gemm1<<<320, 256, 0, stream>>>(ecb, wpeb, b_pe, erep);
  k_fused<<<1256, 256, 0, stream>>>(erep, wpcb, wccb, unionf, b_pc, b_cc, freq, preds, pidx, out);
}

// Round 3
// 615.526 us; speedup vs baseline: 1.2472x; 1.0393x over previous
//
#include <hip/hip_runtime.h>

typedef unsigned short u16;
typedef unsigned int u32;
typedef __attribute__((ext_vector_type(4))) float f32x4;
typedef __attribute__((ext_vector_type(8))) __bf16 bf16x8;
typedef __attribute__((ext_vector_type(8))) u16 u16x8;

// round-to-nearest-even f32 -> bf16 bit pattern
__device__ __forceinline__ u16 f2bf(float x) {
  u32 u = __float_as_uint(x);
  u32 r = (u + 0x7FFFu + ((u >> 16) & 1u)) >> 16;
  return (u16)r;
}

// async global->LDS, 16B per lane. LDS dest = wave-uniform base + lane*16.
__device__ __forceinline__ void gl16(const void* g, void* l) {
  auto* gp = (__attribute__((address_space(1))) u32*)(g);
  auto* lp = (__attribute__((address_space(3))) u32*)(l);
  __builtin_amdgcn_global_load_lds(gp, lp, 16, 0, 0);
}

__device__ __forceinline__ f32x4 mfma16(bf16x8 a, bf16x8 b, f32x4 c) {
  return __builtin_amdgcn_mfma_f32_16x16x32_bf16(a, b, c, 0, 0, 0);
}

// ---------------- conversion kernels ----------------

__global__ void k_cvt(const float* __restrict__ in, u16* __restrict__ out, int n8) {
  int i = blockIdx.x * 256 + threadIdx.x;
  if (i >= n8) return;
  const float4* p = (const float4*)in + (long)i * 2;
  float4 a = p[0], b = p[1];
  u16x8 v;
  v[0] = f2bf(a.x); v[1] = f2bf(a.y); v[2] = f2bf(a.z); v[3] = f2bf(a.w);
  v[4] = f2bf(b.x); v[5] = f2bf(b.y); v[6] = f2bf(b.z); v[7] = f2bf(b.w);
  *(u16x8*)(out + (long)i * 8) = v;
}

// W_cc (51x4096) -> bf16 padded to 64x4096 (rows 51..63 = 0)
__global__ void k_cvt_wcc(const float* __restrict__ wcc, u16* __restrict__ out, int n8) {
  int i = blockIdx.x * 256 + threadIdx.x;
  if (i >= n8) return;
  long base = (long)i * 8;
  int row = (int)(base >> 12);
  int col = (int)(base & 4095);
  u16x8 v;
  if (row < 51) {
    const float4* p = (const float4*)(wcc + (long)row * 4096 + col);
    float4 a = p[0], b = p[1];
    v[0] = f2bf(a.x); v[1] = f2bf(a.y); v[2] = f2bf(a.z); v[3] = f2bf(a.w);
    v[4] = f2bf(b.x); v[5] = f2bf(b.y); v[6] = f2bf(b.z); v[7] = f2bf(b.w);
  } else {
#pragma unroll
    for (int j = 0; j < 8; ++j) v[j] = 0;
  }
  *(u16x8*)(out + base) = v;
}

// one 128x128x32 compute step: 8 ds_read_b128 + 16 MFMA (setprio'd)
__device__ __forceinline__ void cstep(const char* sA, const char* sB,
                                      const int (&aOff)[4], const int (&bOff)[4],
                                      f32x4 (&acc)[4][4]) {
  bf16x8 af[4], bv[4];
#pragma unroll
  for (int mi = 0; mi < 4; ++mi) af[mi] = *(const bf16x8*)(sA + aOff[mi]);
#pragma unroll
  for (int ni = 0; ni < 4; ++ni) bv[ni] = *(const bf16x8*)(sB + bOff[ni]);
  __builtin_amdgcn_s_setprio(1);
#pragma unroll
  for (int mi = 0; mi < 4; ++mi)
#pragma unroll
    for (int ni = 0; ni < 4; ++ni)
      acc[mi][ni] = mfma16(af[mi], bv[ni], acc[mi][ni]);
  __builtin_amdgcn_s_setprio(0);
}

// ---------------- GEMM1: edge_rep = relu(edge_ctx @ W_pe.T + b_pe) -> bf16 ----------------
// A: [5000][512] bf16, B(W_pe): [1024][512] bf16, out: [5000][1024] bf16
// 4-deep circular staging, counted vmcnt.
__global__ __launch_bounds__(256, 2) void k_gemm1(const u16* __restrict__ A, const u16* __restrict__ B,
                                                  const float* __restrict__ bias, u16* __restrict__ outp) {
  __shared__ char lds[65536];  // 4 bufs x (A 8K + B 8K)
  int bx = blockIdx.x;
  int rb = bx >> 3, nb = bx & 7;
  int rowBase = rb * 128, nBase = nb * 128;
  int t = threadIdx.x, lane = t & 63, wid = t >> 6;
  int wr = wid >> 1, wc = wid & 1, lm = lane & 15, lg = lane >> 4;
  int ar0 = t >> 2, ar1 = 64 + ar0, c4 = t & 3;
  int sw0 = (c4 * 16) ^ (((ar0 >> 1) & 3) << 4);
  int sw1 = (c4 * 16) ^ (((ar1 >> 1) & 3) << 4);
  const char* aS0 = (const char*)(A + (long)min(rowBase + ar0, 4999) * 512) + sw0;
  const char* aS1 = (const char*)(A + (long)min(rowBase + ar1, 4999) * 512) + sw1;
  const char* bS0 = (const char*)(B + (long)(nBase + ar0) * 512) + sw0;
  const char* bS1 = (const char*)(B + (long)(nBase + ar1) * 512) + sw1;
  int t16 = t * 16;
  int aOff[4], bOff[4];
#pragma unroll
  for (int mi = 0; mi < 4; ++mi) { int r = wr * 64 + mi * 16 + lm; aOff[mi] = r * 64 + ((lg * 16) ^ (((r >> 1) & 3) << 4)); }
#pragma unroll
  for (int ni = 0; ni < 4; ++ni) { int r = wc * 64 + ni * 16 + lm; bOff[ni] = r * 64 + ((lg * 16) ^ (((r >> 1) & 3) << 4)); }
  f32x4 acc[4][4] = {};

#define STAGE_G(k, sb) do { \
    gl16(aS0 + (k) * 2, (sb) + t16); gl16(aS1 + (k) * 2, (sb) + 4096 + t16); \
    gl16(bS0 + (k) * 2, (sb) + 8192 + t16); gl16(bS1 + (k) * 2, (sb) + 12288 + t16); \
  } while (0)

  // prologue: stage tiles 0,1,2
  STAGE_G(0, lds);
  STAGE_G(32, lds + 16384);
  STAGE_G(64, lds + 32768);

  int cur = 0, stg = 3;
  for (int kt = 0; kt < 16; ++kt) {
    if (kt < 13) {
      char* sb = lds + stg * 16384;
      STAGE_G((kt + 3) * 32, sb);
    }
    if (kt < 13)       asm volatile("s_waitcnt vmcnt(12)" ::: "memory");
    else if (kt == 13) asm volatile("s_waitcnt vmcnt(8)" ::: "memory");
    else if (kt == 14) asm volatile("s_waitcnt vmcnt(4)" ::: "memory");
    else               asm volatile("s_waitcnt vmcnt(0)" ::: "memory");
    __builtin_amdgcn_s_barrier();
    char* cb = lds + cur * 16384;
    cstep(cb, cb + 8192, aOff, bOff, acc);
    __builtin_amdgcn_s_barrier();
    cur = (cur == 3) ? 0 : cur + 1;
    stg = (stg == 3) ? 0 : stg + 1;
  }
#undef STAGE_G

#pragma unroll
  for (int mi = 0; mi < 4; ++mi)
#pragma unroll
    for (int ni = 0; ni < 4; ++ni) {
      int n = nBase + wc * 64 + ni * 16 + lm;
      float bvv = bias[n];
#pragma unroll
      for (int rg = 0; rg < 4; ++rg) {
        int r = rowBase + wr * 64 + mi * 16 + lg * 4 + rg;
        if (r < 5000) {
          float v = acc[mi][ni][rg] + bvv;
          v = v > 0.f ? v : 0.f;
          outp[(long)r * 1024 + n] = f2bf(v);
        }
      }
    }
}

// ---------------- fused: GEMM2 + bias + *union + GEMM3 + bias + freq ----------------
// grid = 157 row-blocks * 8 pc-slices. Each block: 128 rows x 512 pc cols (4 chunks of 128).
// 4-deep circular staging with counted vmcnt (T3+T4), setprio on MFMA (T5).
__global__ __launch_bounds__(256, 2) void k_fused(
    const u16* __restrict__ erep,  // [5000][1024] bf16
    const u16* __restrict__ wpc,   // [4096][1024] bf16
    const u16* __restrict__ wcc,   // [64][4096] bf16 (padded)
    const float* __restrict__ un,  // [20000][4096] f32
    const float* __restrict__ bpc, const float* __restrict__ bcc,
    const float* __restrict__ freq, const int* __restrict__ preds,
    const int* __restrict__ pidx, float* __restrict__ outp) {
  __shared__ char lds[81920];
  // buf i (i=0..3): lds + i*16384  (A tile 8K, B tile 8K)
  char* sU = lds;             // 32 KB [128][128] bf16 swizzled — aliases buf0+buf1 (safe: K-loop drained)
  char* sW = lds + 65536;     // 16 KB [64][128] bf16 swizzled

  int bx = blockIdx.x;
  int rb = bx >> 3, ps = bx & 7;
  int rowBase = rb * 128;
  int t = threadIdx.x, lane = t & 63, wid = t >> 6;
  int wr = wid >> 1, wc = wid & 1, lm = lane & 15, lg = lane >> 4;

  int ar0 = t >> 2, ar1 = 64 + ar0, c4 = t & 3;
  int rG0 = min(rowBase + ar0, 19999), rG1 = min(rowBase + ar1, 19999);
  int hi0 = pidx[2 * rG0], ti0 = pidx[2 * rG0 + 1];
  int hi1 = pidx[2 * rG1], ti1 = pidx[2 * rG1 + 1];
  int sw0 = (c4 * 16) ^ (((ar0 >> 1) & 3) << 4);
  int sw1 = (c4 * 16) ^ (((ar1 >> 1) & 3) << 4);
  const char* aR0h = (const char*)(erep + (long)hi0 * 1024) + sw0;
  const char* aR0t = (const char*)(erep + (long)ti0 * 1024) + sw0;
  const char* aR1h = (const char*)(erep + (long)hi1 * 1024) + sw1;
  const char* aR1t = (const char*)(erep + (long)ti1 * 1024) + sw1;
  int t16 = t * 16;

  int aOff[4], bOff[4];
#pragma unroll
  for (int mi = 0; mi < 4; ++mi) { int r = wr * 64 + mi * 16 + lm; aOff[mi] = r * 64 + ((lg * 16) ^ (((r >> 1) & 3) << 4)); }
#pragma unroll
  for (int ni = 0; ni < 4; ++ni) { int r = wc * 64 + ni * 16 + lm; bOff[ni] = r * 64 + ((lg * 16) ^ (((r >> 1) & 3) << 4)); }

  f32x4 outAcc[2][4] = {};

  for (int chk = 0; chk < 4; ++chk) {
    int pcBase = ps * 512 + chk * 128;
    f32x4 acc[4][4] = {};
    const char* bS0 = (const char*)(wpc + (long)(pcBase + ar0) * 1024) + sw0;
    const char* bS1 = (const char*)(wpc + (long)(pcBase + ar1) * 1024) + sw1;

#define STAGE_F(k, sb) do { \
    const char* a0_ = ((k) < 512) ? aR0h : aR0t; \
    const char* a1_ = ((k) < 512) ? aR1h : aR1t; \
    gl16(a0_ + (k) * 2, (sb) + t16); gl16(a1_ + (k) * 2, (sb) + 4096 + t16); \
    gl16(bS0 + (k) * 2, (sb) + 8192 + t16); gl16(bS1 + (k) * 2, (sb) + 12288 + t16); \
  } while (0)

    // ---- chunk prologue: stage W_cc chunk (oldest), then tiles 0,1,2 ----
#pragma unroll
    for (int i = 0; i < 4; ++i) {
      int cc = t + i * 256;
      int row = cc >> 4, c16 = cc & 15;
      const char* src = (const char*)(wcc + (long)row * 4096) + pcBase * 2 + ((c16 * 16) ^ ((row & 7) << 4));
      gl16(src, sW + cc * 16);
    }
    STAGE_F(0, lds);
    STAGE_F(32, lds + 16384);
    STAGE_F(64, lds + 32768);

    // ---- 4-deep pipelined K-loop: 32 tiles of K=32, counted vmcnt ----
    int cur = 0, stg = 3;
    for (int kt = 0; kt < 32; ++kt) {
      if (kt < 29) {
        char* sb = lds + stg * 16384;
        STAGE_F((kt + 3) * 32, sb);
      }
      if (kt < 29)       asm volatile("s_waitcnt vmcnt(12)" ::: "memory");
      else if (kt == 29) asm volatile("s_waitcnt vmcnt(8)" ::: "memory");
      else if (kt == 30) asm volatile("s_waitcnt vmcnt(4)" ::: "memory");
      else               asm volatile("s_waitcnt vmcnt(0)" ::: "memory");
      __builtin_amdgcn_s_barrier();
      char* cb = lds + cur * 16384;
      cstep(cb, cb + 8192, aOff, bOff, acc);
      __builtin_amdgcn_s_barrier();
      cur = (cur == 3) ? 0 : cur + 1;
      stg = (stg == 3) ? 0 : stg + 1;
    }
#undef STAGE_F

    // ---- epilogue: +b_pc, *union, ->bf16 into sU (overwrites buf0/buf1; drained) ----
#pragma unroll
    for (int mi = 0; mi < 4; ++mi)
#pragma unroll
      for (int ni = 0; ni < 4; ++ni) {
        int pl = wc * 64 + ni * 16 + lm;
        float bvv = bpc[pcBase + pl];
#pragma unroll
        for (int rg = 0; rg < 4; ++rg) {
          int r = wr * 64 + mi * 16 + lg * 4 + rg;
          long rG = min(rowBase + r, 19999);
          float u = un[rG * 4096 + pcBase + pl];
          float v = (acc[mi][ni][rg] + bvv) * u;
          *(u16*)(sU + r * 256 + ((pl * 2) ^ ((r & 7) << 4))) = f2bf(v);
        }
      }
    __syncthreads();

    // ---- GEMM3 partial: outAcc += sU(128x128) @ sW(64x128)^T ----
#pragma unroll
    for (int kb = 0; kb < 4; ++kb) {
      bf16x8 aU[2], bW[4];
#pragma unroll
      for (int m2 = 0; m2 < 2; ++m2) {
        int r = wid * 32 + m2 * 16 + lm;
        aU[m2] = *(const bf16x8*)(sU + r * 256 + ((kb * 64 + lg * 16) ^ ((r & 7) << 4)));
      }
#pragma unroll
      for (int ni = 0; ni < 4; ++ni) {
        int r = ni * 16 + lm;
        bW[ni] = *(const bf16x8*)(sW + r * 256 + ((kb * 64 + lg * 16) ^ ((r & 7) << 4)));
      }
#pragma unroll
      for (int m2 = 0; m2 < 2; ++m2)
#pragma unroll
        for (int ni = 0; ni < 4; ++ni)
          outAcc[m2][ni] = mfma16(aU[m2], bW[ni], outAcc[m2][ni]);
    }
    __syncthreads();
  }

  // final: + b_cc + freq (slice 0 only), atomicAdd partials
#pragma unroll
  for (int m2 = 0; m2 < 2; ++m2)
#pragma unroll
    for (int rg = 0; rg < 4; ++rg) {
      int r = wid * 32 + m2 * 16 + lg * 4 + rg;
      int rG = rowBase + r;
      if (rG < 20000) {
        int lbl = 0;
        if (ps == 0) lbl = preds[pidx[2 * rG]] * 151 + preds[pidx[2 * rG + 1]];
#pragma unroll
        for (int ni = 0; ni < 4; ++ni) {
          int c = ni * 16 + lm;
          if (c < 51) {
            float v = outAcc[m2][ni][rg];
            if (ps == 0) v += bcc[c] + freq[(long)lbl * 51 + c];
            atomicAdd(&outp[(long)rG * 51 + c], v);
          }
        }
      }
    }
}

extern "C" void kernel_launch(void* const* d_in, const int* in_sizes, int n_in,
                              void* d_out, int out_size, void* d_ws, size_t ws_size,
                              hipStream_t stream) {
  const float* edge_ctx = (const float*)d_in[0];
  const float* unionf   = (const float*)d_in[1];
  const float* W_pe     = (const float*)d_in[2];
  const float* b_pe     = (const float*)d_in[3];
  const float* W_pc     = (const float*)d_in[4];
  const float* b_pc     = (const float*)d_in[5];
  const float* W_cc     = (const float*)d_in[6];
  const float* b_cc     = (const float*)d_in[7];
  const float* freq     = (const float*)d_in[8];
  const int*   preds    = (const int*)d_in[9];
  const int*   pidx     = (const int*)d_in[10];
  float* out = (float*)d_out;
  char* ws = (char*)d_ws;

  u16* ecb  = (u16*)(ws + 0);         // 5000*512   bf16 edge_ctx
  u16* wpeb = (u16*)(ws + 5120000);   // 1024*512   bf16 W_pe
  u16* erep = (u16*)(ws + 6168576);   // 5000*1024  bf16 edge_rep (relu'd)
  u16* wpcb = (u16*)(ws + 16408576);  // 4096*1024  bf16 W_pc
  u16* wccb = (u16*)(ws + 24797184);  // 64*4096    bf16 W_cc padded

  hipMemsetAsync(d_out, 0, (size_t)out_size * 4, stream);
  k_cvt<<<1250, 256, 0, stream>>>(edge_ctx, ecb, 320000);
  k_cvt<<<256, 256, 0, stream>>>(W_pe, wpeb, 65536);
  k_cvt<<<2048, 256, 0, stream>>>(W_pc, wpcb, 524288);
  k_cvt_wcc<<<128, 256, 0, stream>>>(W_cc, wccb, 32768);
  k_gemm1<<<320, 256, 0, stream>>>(ecb, wpeb, b_pe, erep);
  k_fused<<<1256, 256, 0, stream>>>(erep, wpcb, wccb, unionf, b_pc, b_cc, freq, preds, pidx, out);
}

// Round 4
// 259.977 us; speedup vs baseline: 2.9528x; 2.3676x over previous
//
#include <hip/hip_runtime.h>

typedef unsigned short u16;
typedef unsigned int u32;
typedef __attribute__((ext_vector_type(4))) float f32x4;
typedef __attribute__((ext_vector_type(8))) __bf16 bf16x8;
typedef __attribute__((ext_vector_type(8))) u16 u16x8;

// round-to-nearest-even f32 -> bf16 bit pattern
__device__ __forceinline__ u16 f2bf(float x) {
  u32 u = __float_as_uint(x);
  u32 r = (u + 0x7FFFu + ((u >> 16) & 1u)) >> 16;
  return (u16)r;
}

__device__ __forceinline__ float bf2f(u16 b) {
  return __uint_as_float((u32)b << 16);
}

// async global->LDS, 16B per lane. LDS dest = wave-uniform base + lane*16.
__device__ __forceinline__ void gl16(const void* g, void* l) {
  auto* gp = (__attribute__((address_space(1))) u32*)(g);
  auto* lp = (__attribute__((address_space(3))) u32*)(l);
  __builtin_amdgcn_global_load_lds(gp, lp, 16, 0, 0);
}

__device__ __forceinline__ f32x4 mfma16(bf16x8 a, bf16x8 b, f32x4 c) {
  return __builtin_amdgcn_mfma_f32_16x16x32_bf16(a, b, c, 0, 0, 0);
}

// ---------------- conversion kernels ----------------

__global__ void k_cvt(const float* __restrict__ in, u16* __restrict__ out, int n8) {
  int i = blockIdx.x * 256 + threadIdx.x;
  if (i >= n8) return;
  const float4* p = (const float4*)in + (long)i * 2;
  float4 a = p[0], b = p[1];
  u16x8 v;
  v[0] = f2bf(a.x); v[1] = f2bf(a.y); v[2] = f2bf(a.z); v[3] = f2bf(a.w);
  v[4] = f2bf(b.x); v[5] = f2bf(b.y); v[6] = f2bf(b.z); v[7] = f2bf(b.w);
  *(u16x8*)(out + (long)i * 8) = v;
}

// W_cc (51x4096) -> bf16 padded to 64x4096 (rows 51..63 = 0)
__global__ void k_cvt_wcc(const float* __restrict__ wcc, u16* __restrict__ out, int n8) {
  int i = blockIdx.x * 256 + threadIdx.x;
  if (i >= n8) return;
  long base = (long)i * 8;
  int row = (int)(base >> 12);
  int col = (int)(base & 4095);
  u16x8 v;
  if (row < 51) {
    const float4* p = (const float4*)(wcc + (long)row * 4096 + col);
    float4 a = p[0], b = p[1];
    v[0] = f2bf(a.x); v[1] = f2bf(a.y); v[2] = f2bf(a.z); v[3] = f2bf(a.w);
    v[4] = f2bf(b.x); v[5] = f2bf(b.y); v[6] = f2bf(b.z); v[7] = f2bf(b.w);
  } else {
#pragma unroll
    for (int j = 0; j < 8; ++j) v[j] = 0;
  }
  *(u16x8*)(out + base) = v;
}

// one 128x128x32 compute step: 8 ds_read_b128 + 16 MFMA (setprio'd)
__device__ __forceinline__ void cstep(const char* sA, const char* sB,
                                      const int (&aOff)[4], const int (&bOff)[4],
                                      f32x4 (&acc)[4][4]) {
  bf16x8 af[4], bv[4];
#pragma unroll
  for (int mi = 0; mi < 4; ++mi) af[mi] = *(const bf16x8*)(sA + aOff[mi]);
#pragma unroll
  for (int ni = 0; ni < 4; ++ni) bv[ni] = *(const bf16x8*)(sB + bOff[ni]);
  __builtin_amdgcn_s_setprio(1);
#pragma unroll
  for (int mi = 0; mi < 4; ++mi)
#pragma unroll
    for (int ni = 0; ni < 4; ++ni)
      acc[mi][ni] = mfma16(af[mi], bv[ni], acc[mi][ni]);
  __builtin_amdgcn_s_setprio(0);
}

// ---------------- GEMM1: edge_rep = relu(edge_ctx @ W_pe.T + b_pe) -> bf16 ----------------
// A: [5000][512] bf16, B(W_pe): [1024][512] bf16, out: [5000][1024] bf16
__global__ __launch_bounds__(256, 2) void k_gemm1(const u16* __restrict__ A, const u16* __restrict__ B,
                                                  const float* __restrict__ bias, u16* __restrict__ outp) {
  __shared__ char lds[65536];  // 4 bufs x (A 8K + B 8K)
  int bx = blockIdx.x;
  int rb = bx >> 3, nb = bx & 7;
  int rowBase = rb * 128, nBase = nb * 128;
  int t = threadIdx.x, lane = t & 63, wid = t >> 6;
  int wr = wid >> 1, wc = wid & 1, lm = lane & 15, lg = lane >> 4;
  int ar0 = t >> 2, ar1 = 64 + ar0, c4 = t & 3;
  int sw0 = (c4 * 16) ^ (((ar0 >> 1) & 3) << 4);
  int sw1 = (c4 * 16) ^ (((ar1 >> 1) & 3) << 4);
  const char* aS0 = (const char*)(A + (long)min(rowBase + ar0, 4999) * 512) + sw0;
  const char* aS1 = (const char*)(A + (long)min(rowBase + ar1, 4999) * 512) + sw1;
  const char* bS0 = (const char*)(B + (long)(nBase + ar0) * 512) + sw0;
  const char* bS1 = (const char*)(B + (long)(nBase + ar1) * 512) + sw1;
  int t16 = t * 16;
  int aOff[4], bOff[4];
#pragma unroll
  for (int mi = 0; mi < 4; ++mi) { int r = wr * 64 + mi * 16 + lm; aOff[mi] = r * 64 + ((lg * 16) ^ (((r >> 1) & 3) << 4)); }
#pragma unroll
  for (int ni = 0; ni < 4; ++ni) { int r = wc * 64 + ni * 16 + lm; bOff[ni] = r * 64 + ((lg * 16) ^ (((r >> 1) & 3) << 4)); }
  f32x4 acc[4][4] = {};

#define STAGE_G(k, sb) do { \
    gl16(aS0 + (k) * 2, (sb) + t16); gl16(aS1 + (k) * 2, (sb) + 4096 + t16); \
    gl16(bS0 + (k) * 2, (sb) + 8192 + t16); gl16(bS1 + (k) * 2, (sb) + 12288 + t16); \
  } while (0)

  STAGE_G(0, lds);
  STAGE_G(32, lds + 16384);
  STAGE_G(64, lds + 32768);

  int cur = 0, stg = 3;
  for (int kt = 0; kt < 16; ++kt) {
    if (kt < 13) {
      char* sb = lds + stg * 16384;
      STAGE_G((kt + 3) * 32, sb);
    }
    if (kt < 13)       asm volatile("s_waitcnt vmcnt(12)" ::: "memory");
    else if (kt == 13) asm volatile("s_waitcnt vmcnt(8)" ::: "memory");
    else if (kt == 14) asm volatile("s_waitcnt vmcnt(4)" ::: "memory");
    else               asm volatile("s_waitcnt vmcnt(0)" ::: "memory");
    __builtin_amdgcn_s_barrier();
    char* cb = lds + cur * 16384;
    cstep(cb, cb + 8192, aOff, bOff, acc);
    __builtin_amdgcn_s_barrier();
    cur = (cur == 3) ? 0 : cur + 1;
    stg = (stg == 3) ? 0 : stg + 1;
  }
#undef STAGE_G

#pragma unroll
  for (int mi = 0; mi < 4; ++mi)
#pragma unroll
    for (int ni = 0; ni < 4; ++ni) {
      int n = nBase + wc * 64 + ni * 16 + lm;
      float bvv = bias[n];
#pragma unroll
      for (int rg = 0; rg < 4; ++rg) {
        int r = rowBase + wr * 64 + mi * 16 + lg * 4 + rg;
        if (r < 5000) {
          float v = acc[mi][ni][rg] + bvv;
          v = v > 0.f ? v : 0.f;
          outp[(long)r * 1024 + n] = f2bf(v);
        }
      }
    }
}

// ---------------- GEMM2': H = head_rep @ W_pc[:,:512].T + b_pc ; T = tail_rep @ W_pc[:,512:].T ----------------
// erep: [5000][1024] bf16 (ld 1024), wpc: [4096][1024] bf16 (ld 1024).
// grid = 2560: h = bx>=1280, then rb(40) x nb(32). Out: [5000][4096] bf16 each.
__global__ __launch_bounds__(256, 2) void k_gemm2(const u16* __restrict__ erep, const u16* __restrict__ wpc,
                                                  const float* __restrict__ bpc, u16* __restrict__ Hout,
                                                  u16* __restrict__ Tout) {
  __shared__ char lds[65536];
  int bx = blockIdx.x;
  int h = (bx >= 1280) ? 1 : 0;
  int rr = bx - h * 1280;
  int rb = rr >> 5, nb = rr & 31;
  int rowBase = rb * 128, nBase = nb * 128;
  u16* outp = h ? Tout : Hout;
  int t = threadIdx.x, lane = t & 63, wid = t >> 6;
  int wr = wid >> 1, wc = wid & 1, lm = lane & 15, lg = lane >> 4;
  int ar0 = t >> 2, ar1 = 64 + ar0, c4 = t & 3;
  int sw0 = (c4 * 16) ^ (((ar0 >> 1) & 3) << 4);
  int sw1 = (c4 * 16) ^ (((ar1 >> 1) & 3) << 4);
  const char* aS0 = (const char*)(erep + (long)min(rowBase + ar0, 4999) * 1024 + h * 512) + sw0;
  const char* aS1 = (const char*)(erep + (long)min(rowBase + ar1, 4999) * 1024 + h * 512) + sw1;
  const char* bS0 = (const char*)(wpc + (long)(nBase + ar0) * 1024 + h * 512) + sw0;
  const char* bS1 = (const char*)(wpc + (long)(nBase + ar1) * 1024 + h * 512) + sw1;
  int t16 = t * 16;
  int aOff[4], bOff[4];
#pragma unroll
  for (int mi = 0; mi < 4; ++mi) { int r = wr * 64 + mi * 16 + lm; aOff[mi] = r * 64 + ((lg * 16) ^ (((r >> 1) & 3) << 4)); }
#pragma unroll
  for (int ni = 0; ni < 4; ++ni) { int r = wc * 64 + ni * 16 + lm; bOff[ni] = r * 64 + ((lg * 16) ^ (((r >> 1) & 3) << 4)); }
  f32x4 acc[4][4] = {};

#define STAGE_G2(k, sb) do { \
    gl16(aS0 + (k) * 2, (sb) + t16); gl16(aS1 + (k) * 2, (sb) + 4096 + t16); \
    gl16(bS0 + (k) * 2, (sb) + 8192 + t16); gl16(bS1 + (k) * 2, (sb) + 12288 + t16); \
  } while (0)

  STAGE_G2(0, lds);
  STAGE_G2(32, lds + 16384);
  STAGE_G2(64, lds + 32768);

  int cur = 0, stg = 3;
  for (int kt = 0; kt < 16; ++kt) {
    if (kt < 13) {
      char* sb = lds + stg * 16384;
      STAGE_G2((kt + 3) * 32, sb);
    }
    if (kt < 13)       asm volatile("s_waitcnt vmcnt(12)" ::: "memory");
    else if (kt == 13) asm volatile("s_waitcnt vmcnt(8)" ::: "memory");
    else if (kt == 14) asm volatile("s_waitcnt vmcnt(4)" ::: "memory");
    else               asm volatile("s_waitcnt vmcnt(0)" ::: "memory");
    __builtin_amdgcn_s_barrier();
    char* cb = lds + cur * 16384;
    cstep(cb, cb + 8192, aOff, bOff, acc);
    __builtin_amdgcn_s_barrier();
    cur = (cur == 3) ? 0 : cur + 1;
    stg = (stg == 3) ? 0 : stg + 1;
  }
#undef STAGE_G2

#pragma unroll
  for (int mi = 0; mi < 4; ++mi)
#pragma unroll
    for (int ni = 0; ni < 4; ++ni) {
      int n = nBase + wc * 64 + ni * 16 + lm;
      float bvv = h ? 0.f : bpc[n];
#pragma unroll
      for (int rg = 0; rg < 4; ++rg) {
        int r = rowBase + wr * 64 + mi * 16 + lg * 4 + rg;
        if (r < 5000) {
          float v = acc[mi][ni][rg] + bvv;
          outp[(long)r * 4096 + n] = f2bf(v);
        }
      }
    }
}

// ---------------- final: P = (H[hi] + T[ti]) * union ; out = P @ W_cc.T + b_cc + freq ----------------
// grid = 157 row-blocks x 4 pc-slices (1024 cols each, 8 chunks of 128). 256 threads.
__global__ __launch_bounds__(256, 2) void k_final(
    const u16* __restrict__ H, const u16* __restrict__ T,
    const u16* __restrict__ wcc,   // [64][4096] bf16 padded
    const float* __restrict__ un,  // [20000][4096] f32
    const float* __restrict__ bcc, const float* __restrict__ freq,
    const int* __restrict__ preds, const int* __restrict__ pidx,
    float* __restrict__ outp) {
  __shared__ char sU[32768];   // [128][128] bf16 swizzled
  __shared__ int sLbl[128];
  int bx = blockIdx.x;
  int rb = bx >> 2, ps = bx & 3;
  int rowBase = rb * 128;
  int t = threadIdx.x, lane = t & 63, wid = t >> 6;
  int lm = lane & 15, lg = lane >> 4;
  int r16 = t >> 4, c16 = t & 15;

  if (t < 128) {
    int rG = min(rowBase + t, 19999);
    sLbl[t] = preds[pidx[2 * rG]] * 151 + preds[pidx[2 * rG + 1]];
  }

  // gathered row pointers for the 8 passes (16 threads share a row)
  const u16* hp[8];
  const u16* tp[8];
#pragma unroll
  for (int p = 0; p < 8; ++p) {
    int rG = min(rowBase + p * 16 + r16, 19999);
    hp[p] = H + (long)pidx[2 * rG] * 4096;
    tp[p] = T + (long)pidx[2 * rG + 1] * 4096;
  }

  f32x4 outAcc[2][4] = {};

  for (int chk = 0; chk < 8; ++chk) {
    int pcBase = ps * 1024 + chk * 128;
    if (chk) __builtin_amdgcn_s_barrier();  // sU consumed by previous GEMM3
#pragma unroll
    for (int p = 0; p < 8; ++p) {
      int r = p * 16 + r16;
      long rG = min(rowBase + r, 19999);
      u16x8 h8 = *(const u16x8*)(hp[p] + pcBase + c16 * 8);
      u16x8 t8 = *(const u16x8*)(tp[p] + pcBase + c16 * 8);
      float4 u0 = *(const float4*)(un + rG * 4096 + pcBase + c16 * 8);
      float4 u1 = *(const float4*)(un + rG * 4096 + pcBase + c16 * 8 + 4);
      float uu[8];
      *(float4*)(uu) = u0;
      *(float4*)(uu + 4) = u1;
      u16x8 pv;
#pragma unroll
      for (int j = 0; j < 8; ++j)
        pv[j] = f2bf((bf2f(h8[j]) + bf2f(t8[j])) * uu[j]);
      *(u16x8*)(sU + r * 256 + ((c16 * 16) ^ ((r & 7) << 4))) = pv;
    }
    __syncthreads();

    // GEMM3 partial: outAcc += sU(128x128) @ W_cc_chunk(64x128)^T
    // W_cc fragments loaded directly from global (L2-resident, 512 KB)
#pragma unroll
    for (int kb = 0; kb < 4; ++kb) {
      bf16x8 aU[2], bW[4];
#pragma unroll
      for (int m2 = 0; m2 < 2; ++m2) {
        int r = wid * 32 + m2 * 16 + lm;
        aU[m2] = *(const bf16x8*)(sU + r * 256 + ((kb * 64 + lg * 16) ^ ((r & 7) << 4)));
      }
#pragma unroll
      for (int ni = 0; ni < 4; ++ni)
        bW[ni] = *(const bf16x8*)(wcc + (long)(ni * 16 + lm) * 4096 + pcBase + kb * 32 + lg * 8);
      __builtin_amdgcn_s_setprio(1);
#pragma unroll
      for (int m2 = 0; m2 < 2; ++m2)
#pragma unroll
        for (int ni = 0; ni < 4; ++ni)
          outAcc[m2][ni] = mfma16(aU[m2], bW[ni], outAcc[m2][ni]);
      __builtin_amdgcn_s_setprio(0);
    }
  }

  // epilogue: + b_cc + freq (slice 0 only), atomicAdd partials
#pragma unroll
  for (int m2 = 0; m2 < 2; ++m2)
#pragma unroll
    for (int rg = 0; rg < 4; ++rg) {
      int r = wid * 32 + m2 * 16 + lg * 4 + rg;
      int rG = rowBase + r;
      if (rG < 20000) {
#pragma unroll
        for (int ni = 0; ni < 4; ++ni) {
          int c = ni * 16 + lm;
          if (c < 51) {
            float v = outAcc[m2][ni][rg];
            if (ps == 0) v += bcc[c] + freq[(long)sLbl[r] * 51 + c];
            atomicAdd(&outp[(long)rG * 51 + c], v);
          }
        }
      }
    }
}

extern "C" void kernel_launch(void* const* d_in, const int* in_sizes, int n_in,
                              void* d_out, int out_size, void* d_ws, size_t ws_size,
                              hipStream_t stream) {
  const float* edge_ctx = (const float*)d_in[0];
  const float* unionf   = (const float*)d_in[1];
  const float* W_pe     = (const float*)d_in[2];
  const float* b_pe     = (const float*)d_in[3];
  const float* W_pc     = (const float*)d_in[4];
  const float* b_pc     = (const float*)d_in[5];
  const float* W_cc     = (const float*)d_in[6];
  const float* b_cc     = (const float*)d_in[7];
  const float* freq     = (const float*)d_in[8];
  const int*   preds    = (const int*)d_in[9];
  const int*   pidx     = (const int*)d_in[10];
  float* out = (float*)d_out;
  char* ws = (char*)d_ws;

  u16* Hb   = (u16*)(ws + 0);           // 5000*4096 bf16 = 40,960,000 B
  u16* Tb   = (u16*)(ws + 40960000);    // 5000*4096 bf16
  u16* erep = (u16*)(ws + 81920000);    // 5000*1024 bf16 = 10,240,000 B
  u16* wpcb = (u16*)(ws + 92160000);    // 4096*1024 bf16 = 8,388,608 B
  u16* wccb = (u16*)(ws + 100548608);   // 64*4096  bf16 = 524,288 B
  u16* ecb  = (u16*)(ws + 101072896);   // 5000*512 bf16 = 5,120,000 B
  u16* wpeb = (u16*)(ws + 106192896);   // 1024*512 bf16 = 1,048,576 B  (total ~107.2 MB)

  hipMemsetAsync(d_out, 0, (size_t)out_size * 4, stream);
  k_cvt<<<1250, 256, 0, stream>>>(edge_ctx, ecb, 320000);
  k_cvt<<<256, 256, 0, stream>>>(W_pe, wpeb, 65536);
  k_cvt<<<2048, 256, 0, stream>>>(W_pc, wpcb, 524288);
  k_cvt_wcc<<<128, 256, 0, stream>>>(W_cc, wccb, 32768);
  k_gemm1<<<320, 256, 0, stream>>>(ecb, wpeb, b_pe, erep);
  k_gemm2<<<2560, 256, 0, stream>>>(erep, wpcb, b_pc, Hb, Tb);
  k_final<<<628, 256, 0, stream>>>(Hb, Tb, wccb, unionf, b_cc, freq, preds, pidx, out);
}